// Round 2
// baseline (887.095 us; speedup 1.0000x reference)
//
#include <hip/hip_runtime.h>
#include <hip/hip_bf16.h>
#include <math.h>

#define T_TOKENS 16384
#define H_DIM    4096
#define N_EXP    64
#define WAVES    16
#define KRANGE   (H_DIM / WAVES)   // 256 k per wave
#define KB       16                // k-step per iteration (64B/lane)
#define NB       128               // dispatch chunks of 256 assignments

// ---------------- Kernel 1: fused gate GEMM + softmax + top2 + hist ----------
// 256 blocks x 1024 threads (16 waves). Block owns 64 tokens (lane = token).
// Wave w owns k-slice [w*256, w*256+256). x via per-lane vector loads
// (register double-buffered); W via wave-uniform reads -> scalar pipe.
__global__ __launch_bounds__(1024, 4)
void gate_fused(const float* __restrict__ x, const float* __restrict__ W,
                float* __restrict__ out, int* __restrict__ sel,
                int* __restrict__ hist) {
  const int t    = threadIdx.x;
  const int w    = t >> 6;
  const int lane = t & 63;
  const int tokbase = blockIdx.x * 64;
  const int tok  = tokbase + lane;
  const int k0   = w * KRANGE;

  float acc[N_EXP];
  #pragma unroll
  for (int e = 0; e < N_EXP; ++e) acc[e] = 0.f;

  const float* xrow = x + (size_t)tok * H_DIM + k0;
  float4 c0 = *(const float4*)(xrow + 0);
  float4 c1 = *(const float4*)(xrow + 4);
  float4 c2 = *(const float4*)(xrow + 8);
  float4 c3 = *(const float4*)(xrow + 12);

  for (int kb = 0; kb < KRANGE; kb += KB) {
    float4 n0 = c0, n1 = c1, n2 = c2, n3 = c3;
    const int nxt = kb + KB;
    if (nxt < KRANGE) {                 // prefetch next x chunk (uniform branch)
      n0 = *(const float4*)(xrow + nxt + 0);
      n1 = *(const float4*)(xrow + nxt + 4);
      n2 = *(const float4*)(xrow + nxt + 8);
      n3 = *(const float4*)(xrow + nxt + 12);
    }
    float xv[KB];
    xv[0]=c0.x; xv[1]=c0.y; xv[2]=c0.z; xv[3]=c0.w;
    xv[4]=c1.x; xv[5]=c1.y; xv[6]=c1.z; xv[7]=c1.w;
    xv[8]=c2.x; xv[9]=c2.y; xv[10]=c2.z; xv[11]=c2.w;
    xv[12]=c3.x; xv[13]=c3.y; xv[14]=c3.z; xv[15]=c3.w;

    #pragma unroll
    for (int e = 0; e < N_EXP; ++e) {
      const float* wrow = W + (size_t)e * H_DIM + k0 + kb;  // wave-uniform addr
      const float4 w0 = *(const float4*)(wrow + 0);
      const float4 w1 = *(const float4*)(wrow + 4);
      const float4 w2 = *(const float4*)(wrow + 8);
      const float4 w3 = *(const float4*)(wrow + 12);
      float wv[KB];
      wv[0]=w0.x; wv[1]=w0.y; wv[2]=w0.z; wv[3]=w0.w;
      wv[4]=w1.x; wv[5]=w1.y; wv[6]=w1.z; wv[7]=w1.w;
      wv[8]=w2.x; wv[9]=w2.y; wv[10]=w2.z; wv[11]=w2.w;
      wv[12]=w3.x; wv[13]=w3.y; wv[14]=w3.z; wv[15]=w3.w;
      #pragma unroll
      for (int j = 0; j < KB; ++j)
        acc[e] = fmaf(xv[j], wv[j], acc[e]);
    }
    c0 = n0; c1 = n1; c2 = n2; c3 = n3;
  }

  // -------- cross-wave reduction: 8 rounds of 8 experts, pad-9 stride -------
  __shared__ float red[WAVES][64][9];    // 36.9 KiB, conflict-free (gcd(9,32)=1)
  __shared__ float logit[64][65];        // 16.6 KiB
  for (int ec = 0; ec < 8; ++ec) {
    __syncthreads();
    #pragma unroll
    for (int j = 0; j < 8; ++j) red[w][lane][j] = acc[ec * 8 + j];
    __syncthreads();
    if (t < 512) {
      const int lr = t >> 3, j = t & 7;
      float s = 0.f;
      #pragma unroll
      for (int ww = 0; ww < WAVES; ++ww) s += red[ww][lr][j];  // fixed order
      logit[lr][ec * 8 + j] = s;
    }
  }
  __syncthreads();

  // -------- softmax + top-2 + renorm: wave w handles tokens w*4..w*4+3 ------
  for (int tt = 0; tt < 4; ++tt) {
    const int trow = w * 4 + tt;
    const float l = logit[trow][lane];               // lane = expert
    float m = l;
    #pragma unroll
    for (int o = 32; o >= 1; o >>= 1) m = fmaxf(m, __shfl_xor(m, o));
    const float ex = expf(l - m);
    float s = ex;
    #pragma unroll
    for (int o = 32; o >= 1; o >>= 1) s += __shfl_xor(s, o);
    const float p = ex / s;
    // top-1 (tie -> lowest index)
    float v1 = p; int i1 = lane;
    #pragma unroll
    for (int o = 32; o >= 1; o >>= 1) {
      const float ov = __shfl_xor(v1, o); const int oi = __shfl_xor(i1, o);
      if (ov > v1 || (ov == v1 && oi < i1)) { v1 = ov; i1 = oi; }
    }
    // top-2
    float v2 = (lane == i1) ? -INFINITY : p; int i2 = lane;
    #pragma unroll
    for (int o = 32; o >= 1; o >>= 1) {
      const float ov = __shfl_xor(v2, o); const int oi = __shfl_xor(i2, o);
      if (ov > v2 || (ov == v2 && oi < i2)) { v2 = ov; i2 = oi; }
    }
    if (lane == 0) {
      const int gtok = tokbase + trow;
      const float den = v1 + v2;
      out[2 * gtok]     = v1 / den;
      out[2 * gtok + 1] = v2 / den;
      out[2 * T_TOKENS + 2 * gtok]     = (float)i1;
      out[2 * T_TOKENS + 2 * gtok + 1] = (float)i2;
      sel[2 * gtok]     = i1;
      sel[2 * gtok + 1] = i2;
      atomicAdd(&hist[(gtok >> 7) * N_EXP + i1], 1);   // chunk = gtok>>7
      atomicAdd(&hist[(gtok >> 7) * N_EXP + i2], 1);
    }
  }
}

// ---------------- Kernel 2: totals + bases + per-chunk offsets (LDS) --------
__global__ __launch_bounds__(256)
void scan_kernel(const int* __restrict__ hist, int* __restrict__ boff,
                 float* __restrict__ out_msizes) {
  __shared__ int hs[NB * N_EXP];   // 32 KiB
  __shared__ int pt[4][N_EXP];
  __shared__ int base_s[N_EXP];
  const int t = threadIdx.x;
  for (int i = t; i < NB * N_EXP; i += 256) hs[i] = hist[i];
  __syncthreads();
  const int e = t & 63, g = t >> 6;
  int part = 0;
  for (int c = g * 32; c < g * 32 + 32; ++c) part += hs[c * N_EXP + e];
  pt[g][e] = part;
  __syncthreads();
  if (t < 64) {
    const int total = pt[0][e] + pt[1][e] + pt[2][e] + pt[3][e];
    out_msizes[e] = (float)total;
    int incl = total;
    #pragma unroll
    for (int o = 1; o < 64; o <<= 1) {
      const int v = __shfl_up(incl, o);
      if (e >= o) incl += v;
    }
    base_s[e] = incl - total;     // exclusive base
  }
  __syncthreads();
  if (t < 64) {
    int run = base_s[e];
    for (int c = 0; c < NB; ++c) {      // all reads from LDS now
      boff[c * N_EXP + e] = run;
      run += hs[c * N_EXP + e];
    }
  }
}

// ---------------- Kernel 3: stable scatter (counting-sort permutation) ------
__global__ __launch_bounds__(256)
void scatter_kernel(const int* __restrict__ sel, const int* __restrict__ boff,
                    float* __restrict__ out_gather) {
  __shared__ int le[256];
  __shared__ int off[N_EXP];
  const int t = threadIdx.x;
  const int i = blockIdx.x * 256 + t;   // flat assignment index
  const int e = sel[i];
  le[t] = e;
  if (t < N_EXP) off[t] = boff[blockIdx.x * N_EXP + t];
  __syncthreads();
  int rank = 0;
  for (int j = 0; j < 256; ++j)
    rank += (j < t) & (le[j] == e);
  out_gather[off[e] + rank] = (float)i;
}

// ---------------- Launch ----------------
extern "C" void kernel_launch(void* const* d_in, const int* in_sizes, int n_in,
                              void* d_out, int out_size, void* d_ws, size_t ws_size,
                              hipStream_t stream) {
  const float* x = (const float*)d_in[0];   // (16384, 4096)
  const float* W = (const float*)d_in[1];   // (64, 4096)
  float* out = (float*)d_out;               // [w 32768][sel 32768][m 64][g 32768]

  int* sel  = (int*)d_ws;                   // 32768 ints
  int* hist = sel + 2 * T_TOKENS;           // NB*64 ints
  int* boff = hist + NB * N_EXP;            // NB*64 ints

  hipMemsetAsync(hist, 0, NB * N_EXP * sizeof(int), stream);
  hipLaunchKernelGGL(gate_fused, dim3(T_TOKENS / 64), dim3(1024), 0, stream,
                     x, W, out, sel, hist);
  hipLaunchKernelGGL(scan_kernel, dim3(1), dim3(256), 0, stream,
                     hist, boff, out + 4 * T_TOKENS);
  hipLaunchKernelGGL(scatter_kernel, dim3(NB), dim3(256), 0, stream,
                     sel, boff, out + 4 * T_TOKENS + N_EXP);
}

// Round 3
// 620.127 us; speedup vs baseline: 1.4305x; 1.4305x over previous
//
#include <hip/hip_runtime.h>
#include <hip/hip_bf16.h>
#include <math.h>

#define T_TOKENS 16384
#define H_DIM    4096
#define N_EXP    64
#define WAVES    16
#define KRANGE   (H_DIM / WAVES)   // 256 k per wave
#define KB       8                 // k-step per iteration (32B/lane)
#define NB       128               // dispatch chunks of 256 assignments

// ---------------- Kernel 1: fused gate GEMM + softmax + top2 + hist ----------
// 256 blocks x 1024 threads (16 waves) = 1 block/CU, 4 waves/SIMD.
// Block owns 64 tokens (lane = token). Wave w owns k-slice [w*256, w*256+256).
// x: per-lane vector loads, register double-buffered.
// W: wave-uniform scalar loads (readfirstlane base + constant offsets)
//    -> s_load + v_fmac with SGPR operand: zero VALU cost for W.
__global__ __launch_bounds__(1024)
void gate_fused(const float* __restrict__ x, const float* __restrict__ W,
                float* __restrict__ out, int* __restrict__ sel,
                int* __restrict__ hist) {
  const int t    = threadIdx.x;
  const int lane = t & 63;
  const int w    = t >> 6;
  // officially SGPR-uniform wave id -> W addresses become scalar
  const int kw   = __builtin_amdgcn_readfirstlane(w);
  const int k0   = kw * KRANGE;
  const int tokbase = blockIdx.x * 64;
  const int tok  = tokbase + lane;

  float acc[N_EXP];
  #pragma unroll
  for (int e = 0; e < N_EXP; ++e) acc[e] = 0.f;

  const float* xrow = x + (size_t)tok * H_DIM + k0;
  float4 c0 = *(const float4*)(xrow + 0);
  float4 c1 = *(const float4*)(xrow + 4);

  for (int kb = 0; kb < KRANGE; kb += KB) {
    float4 n0, n1;
    const int nxt = kb + KB;
    if (nxt < KRANGE) {               // uniform branch: prefetch next x chunk
      n0 = *(const float4*)(xrow + nxt + 0);
      n1 = *(const float4*)(xrow + nxt + 4);
    } else { n0 = c0; n1 = c1; }

    float xv[KB];
    xv[0]=c0.x; xv[1]=c0.y; xv[2]=c0.z; xv[3]=c0.w;
    xv[4]=c1.x; xv[5]=c1.y; xv[6]=c1.z; xv[7]=c1.w;

    const float* wb = W + k0 + kb;    // uniform base; e*4096+j are imm offsets
    #pragma unroll
    for (int e = 0; e < N_EXP; ++e) {
      #pragma unroll
      for (int j = 0; j < KB; ++j)
        acc[e] = fmaf(xv[j], wb[(size_t)e * H_DIM + j], acc[e]);
    }
    c0 = n0; c1 = n1;
  }

  // -------- cross-wave reduction: 8 rounds of 8 experts, pad-9 stride -------
  __shared__ float red[WAVES][64][9];    // 36 KiB, gcd(9,32)=1
  __shared__ float logit[64][65];        // 16.6 KiB
  #pragma unroll
  for (int ec = 0; ec < 8; ++ec) {       // UNROLLED: acc indices stay static
    __syncthreads();
    #pragma unroll
    for (int j = 0; j < 8; ++j) red[w][lane][j] = acc[ec * 8 + j];
    __syncthreads();
    if (t < 512) {
      const int lr = t >> 3, j = t & 7;
      float s = 0.f;
      #pragma unroll
      for (int ww = 0; ww < WAVES; ++ww) s += red[ww][lr][j];  // fixed order
      logit[lr][ec * 8 + j] = s;
    }
  }
  __syncthreads();

  // -------- softmax + top-2 + renorm: wave w handles tokens w*4..w*4+3 ------
  #pragma unroll
  for (int tt = 0; tt < 4; ++tt) {
    const int trow = w * 4 + tt;
    const float l = logit[trow][lane];               // lane = expert
    float m = l;
    #pragma unroll
    for (int o = 32; o >= 1; o >>= 1) m = fmaxf(m, __shfl_xor(m, o));
    const float ex = expf(l - m);
    float s = ex;
    #pragma unroll
    for (int o = 32; o >= 1; o >>= 1) s += __shfl_xor(s, o);
    const float p = ex / s;
    // top-1 (tie -> lowest index)
    float v1 = p; int i1 = lane;
    #pragma unroll
    for (int o = 32; o >= 1; o >>= 1) {
      const float ov = __shfl_xor(v1, o); const int oi = __shfl_xor(i1, o);
      if (ov > v1 || (ov == v1 && oi < i1)) { v1 = ov; i1 = oi; }
    }
    // top-2
    float v2 = (lane == i1) ? -INFINITY : p; int i2 = lane;
    #pragma unroll
    for (int o = 32; o >= 1; o >>= 1) {
      const float ov = __shfl_xor(v2, o); const int oi = __shfl_xor(i2, o);
      if (ov > v2 || (ov == v2 && oi < i2)) { v2 = ov; i2 = oi; }
    }
    if (lane == 0) {
      const int gtok = tokbase + trow;
      const float den = v1 + v2;
      out[2 * gtok]     = v1 / den;
      out[2 * gtok + 1] = v2 / den;
      out[2 * T_TOKENS + 2 * gtok]     = (float)i1;
      out[2 * T_TOKENS + 2 * gtok + 1] = (float)i2;
      sel[2 * gtok]     = i1;
      sel[2 * gtok + 1] = i2;
      atomicAdd(&hist[(gtok >> 7) * N_EXP + i1], 1);   // chunk = gtok>>7
      atomicAdd(&hist[(gtok >> 7) * N_EXP + i2], 1);
    }
  }
}

// ---------------- Kernel 2: totals + bases + per-chunk offsets (LDS) --------
__global__ __launch_bounds__(256)
void scan_kernel(const int* __restrict__ hist, int* __restrict__ boff,
                 float* __restrict__ out_msizes) {
  __shared__ int hs[NB * N_EXP];   // 32 KiB
  __shared__ int pt[4][N_EXP];
  __shared__ int base_s[N_EXP];
  const int t = threadIdx.x;
  for (int i = t; i < NB * N_EXP; i += 256) hs[i] = hist[i];
  __syncthreads();
  const int e = t & 63, g = t >> 6;
  int part = 0;
  for (int c = g * 32; c < g * 32 + 32; ++c) part += hs[c * N_EXP + e];
  pt[g][e] = part;
  __syncthreads();
  if (t < 64) {
    const int total = pt[0][e] + pt[1][e] + pt[2][e] + pt[3][e];
    out_msizes[e] = (float)total;
    int incl = total;
    #pragma unroll
    for (int o = 1; o < 64; o <<= 1) {
      const int v = __shfl_up(incl, o);
      if (e >= o) incl += v;
    }
    base_s[e] = incl - total;     // exclusive base
  }
  __syncthreads();
  if (t < 64) {
    int run = base_s[e];
    for (int c = 0; c < NB; ++c) {      // all reads from LDS
      boff[c * N_EXP + e] = run;
      run += hs[c * N_EXP + e];
    }
  }
}

// ---------------- Kernel 3: stable scatter (counting-sort permutation) ------
__global__ __launch_bounds__(256)
void scatter_kernel(const int* __restrict__ sel, const int* __restrict__ boff,
                    float* __restrict__ out_gather) {
  __shared__ int le[256];
  __shared__ int off[N_EXP];
  const int t = threadIdx.x;
  const int i = blockIdx.x * 256 + t;   // flat assignment index
  const int e = sel[i];
  le[t] = e;
  if (t < N_EXP) off[t] = boff[blockIdx.x * N_EXP + t];
  __syncthreads();
  int rank = 0;
  for (int j = 0; j < 256; ++j)
    rank += (j < t) & (le[j] == e);
  out_gather[off[e] + rank] = (float)i;
}

// ---------------- Launch ----------------
extern "C" void kernel_launch(void* const* d_in, const int* in_sizes, int n_in,
                              void* d_out, int out_size, void* d_ws, size_t ws_size,
                              hipStream_t stream) {
  const float* x = (const float*)d_in[0];   // (16384, 4096)
  const float* W = (const float*)d_in[1];   // (64, 4096)
  float* out = (float*)d_out;               // [w 32768][sel 32768][m 64][g 32768]

  int* sel  = (int*)d_ws;                   // 32768 ints
  int* hist = sel + 2 * T_TOKENS;           // NB*64 ints
  int* boff = hist + NB * N_EXP;            // NB*64 ints

  hipMemsetAsync(hist, 0, NB * N_EXP * sizeof(int), stream);
  hipLaunchKernelGGL(gate_fused, dim3(T_TOKENS / 64), dim3(1024), 0, stream,
                     x, W, out, sel, hist);
  hipLaunchKernelGGL(scan_kernel, dim3(1), dim3(256), 0, stream,
                     hist, boff, out + 4 * T_TOKENS);
  hipLaunchKernelGGL(scatter_kernel, dim3(NB), dim3(256), 0, stream,
                     sel, boff, out + 4 * T_TOKENS + N_EXP);
}